// Round 3
// baseline (15987.946 us; speedup 1.0000x reference)
//
#include <hip/hip_runtime.h>
#include <math.h>

#define Hh   512
#define G3   1536   // 3*H
#define Tlen 512
#define Bsz  64
#define BH   (Bsz*Hh)   // 32768

__device__ __forceinline__ float sigmoid_f(float x) { return 1.0f / (1.0f + expf(-x)); }

// ---------------------------------------------------------------------------
// GEMM: C[M,N] = A[M,K] @ W[N,K]^T + bias[N]   (fp32, 128x128 tile, 8x8/thread)
// Register double-buffered staging: next k-tile global loads overlap compute.
// M=32768, N=1536, K in {256,512}; all dims divide tiles exactly.
// ---------------------------------------------------------------------------
__global__ __launch_bounds__(256) void gemm_xg(const float* __restrict__ A,
                                               const float* __restrict__ W,
                                               const float* __restrict__ bias,
                                               float* __restrict__ C,
                                               int M, int N, int K) {
  __shared__ float As[16][132];   // [k][m], +4 pad
  __shared__ float Bs[16][132];   // [k][n]
  const int nbm = M >> 7;
  const int bm = blockIdx.x % nbm;
  const int bn = blockIdx.x / nbm;
  const int m0 = bm << 7, n0 = bn << 7;
  const int tid = threadIdx.x;
  const int tx = tid & 15, ty = tid >> 4;

  const int row0 = tid >> 2;          // 0..63
  const int kq0  = (tid & 3) << 2;    // 0,4,8,12

  const float* Ap0 = &A[(size_t)(m0 + row0) * K + kq0];
  const float* Ap1 = &A[(size_t)(m0 + row0 + 64) * K + kq0];
  const float* Wp0 = &W[(size_t)(n0 + row0) * K + kq0];
  const float* Wp1 = &W[(size_t)(n0 + row0 + 64) * K + kq0];

  float4 ra0 = *(const float4*)(Ap0);
  float4 ra1 = *(const float4*)(Ap1);
  float4 rb0 = *(const float4*)(Wp0);
  float4 rb1 = *(const float4*)(Wp1);

  float acc[8][8];
#pragma unroll
  for (int r = 0; r < 8; r++)
#pragma unroll
    for (int c = 0; c < 8; c++) acc[r][c] = 0.0f;

  for (int kk = 0; kk < K; kk += 16) {
    // commit staged registers to LDS
    As[kq0+0][row0]    = ra0.x; As[kq0+1][row0]    = ra0.y; As[kq0+2][row0]    = ra0.z; As[kq0+3][row0]    = ra0.w;
    As[kq0+0][row0+64] = ra1.x; As[kq0+1][row0+64] = ra1.y; As[kq0+2][row0+64] = ra1.z; As[kq0+3][row0+64] = ra1.w;
    Bs[kq0+0][row0]    = rb0.x; Bs[kq0+1][row0]    = rb0.y; Bs[kq0+2][row0]    = rb0.z; Bs[kq0+3][row0]    = rb0.w;
    Bs[kq0+0][row0+64] = rb1.x; Bs[kq0+1][row0+64] = rb1.y; Bs[kq0+2][row0+64] = rb1.z; Bs[kq0+3][row0+64] = rb1.w;
    __syncthreads();
    // issue next k-tile loads; they stay in flight while we compute
    const int kn = kk + 16;
    if (kn < K) {
      ra0 = *(const float4*)(Ap0 + kn);
      ra1 = *(const float4*)(Ap1 + kn);
      rb0 = *(const float4*)(Wp0 + kn);
      rb1 = *(const float4*)(Wp1 + kn);
    }
#pragma unroll
    for (int k = 0; k < 16; k++) {
      float4 a0 = *(const float4*)&As[k][ty << 3];
      float4 a1 = *(const float4*)&As[k][(ty << 3) + 4];
      float4 b0 = *(const float4*)&Bs[k][tx << 3];
      float4 b1 = *(const float4*)&Bs[k][(tx << 3) + 4];
      float ar[8] = {a0.x, a0.y, a0.z, a0.w, a1.x, a1.y, a1.z, a1.w};
      float br[8] = {b0.x, b0.y, b0.z, b0.w, b1.x, b1.y, b1.z, b1.w};
#pragma unroll
      for (int r = 0; r < 8; r++)
#pragma unroll
        for (int c = 0; c < 8; c++) acc[r][c] = fmaf(ar[r], br[c], acc[r][c]);
    }
    __syncthreads();
  }
  // epilogue with bias
  float bl[8];
#pragma unroll
  for (int c = 0; c < 8; c++) bl[c] = bias[n0 + (tx << 3) + c];
#pragma unroll
  for (int r = 0; r < 8; r++) {
    int m = m0 + (ty << 3) + r;
    float4 o0 = make_float4(acc[r][0] + bl[0], acc[r][1] + bl[1], acc[r][2] + bl[2], acc[r][3] + bl[3]);
    float4 o1 = make_float4(acc[r][4] + bl[4], acc[r][5] + bl[5], acc[r][6] + bl[6], acc[r][7] + bl[7]);
    *(float4*)&C[(size_t)m * N + n0 + (tx << 3)]     = o0;
    *(float4*)&C[(size_t)m * N + n0 + (tx << 3) + 4] = o1;
  }
}

// ---------------------------------------------------------------------------
// GRU scan (one layer). 256 blocks x 256 threads.
// 8 INDEPENDENT batch-groups of 32 blocks (bgrp = blockIdx&7 -> same XCD
// under round-robin dispatch heuristic; correctness is placement-independent).
// Stamp-slot barrier: each block release-stores step stamp to its OWN 128B
// slot (no contention); wave 0 spins with lane-parallel acquire loads.
// Block = (bgrp: 8 batches) x (jgrp: 16 hidden j). Thread = (jl, ks).
// W_hh slice (3 gates x 32 k) lives in registers for the whole scan.
// h staged per-step into LDS with XOR swizzle to avoid bank conflicts.
// xg[t+1] prefetch issued between release and spin -> hidden under barrier.
// ---------------------------------------------------------------------------
__global__ __launch_bounds__(256, 1) void gru_scan(
    const float* __restrict__ xg,   // [T, B, 3H]
    const float* __restrict__ Whh,  // [3H, H]
    const float* __restrict__ bhh,  // [3H]
    float* __restrict__ y,          // [T, B, H]
    float* __restrict__ hfin,       // [B, H] final hidden
    float* hbuf,                    // 2 slots of [B][H]
    int* slots,                     // 8 groups x 32 blocks x 32-int stride
    int base) {                     // stamp base (0 for layer0, Tlen for layer1)
  const int tid = threadIdx.x;
  const int jl = tid >> 4;          // 0..15  hidden-j within block
  const int ks = tid & 15;          // 0..15  k-chunk (32 floats each)
  const int bgrp = blockIdx.x & 7;
  const int jgrp = blockIdx.x >> 3; // 0..31
  const int j0 = jgrp << 4;
  const int b0 = bgrp << 3;
  const int k0 = ks << 5;

  int* myslot = slots + (bgrp * 32 + jgrp) * 32;
  int* gslots = slots + bgrp * 32 * 32;

  __shared__ float4 hs4[8 * 128];   // 8 batch rows x 128 float4 (swizzled)

  // persistent W_hh fragment: 3 gates x 32 floats
  float4 wv[3][8];
#pragma unroll
  for (int g = 0; g < 3; g++) {
    const float* wp = &Whh[(size_t)(g * Hh + j0 + jl) * Hh + k0];
#pragma unroll
    for (int q = 0; q < 8; q++) wv[g][q] = *(const float4*)&wp[q * 4];
  }
  float bh[3];
#pragma unroll
  for (int g = 0; g < 3; g++) bh[g] = bhh[g * Hh + j0 + jl];

  // precomputed swizzled LDS float4 offsets for this thread's k-chunk
  int off[8];
#pragma unroll
  for (int q = 0; q < 8; q++) off[q] = (ks * 8 + q) ^ (ks & 7);

  // prologue: xg[0]
  float xr = 0.0f, xz = 0.0f, xn = 0.0f;
  if (ks < 8) {
    const float* xp = &xg[(size_t)(b0 + ks) * G3 + j0 + jl];
    xr = xp[0]; xz = xp[Hh]; xn = xp[2 * Hh];
  }

  int cur = 0;

  for (int t = 0; t < Tlen; t++) {
    // ---- stage h_prev rows [b0, b0+8) into LDS (swizzled) ----
    const float4* hsrc = (const float4*)(hbuf + cur * BH);
#pragma unroll
    for (int i = 0; i < 4; i++) {
      int idx = tid + i * 256;            // 0..1023
      int b = idx >> 7, f = idx & 127;
      float4 v = hsrc[(size_t)(b0 + b) * 128 + f];
      hs4[b * 128 + (f ^ ((f >> 3) & 7))] = v;
    }
    __syncthreads();

    // ---- partial dots: 3 gates x 8 batches over this thread's 32 k ----
    float acc[3][8];
#pragma unroll
    for (int b = 0; b < 8; b++) {
      float4 hv[8];
#pragma unroll
      for (int q = 0; q < 8; q++) hv[q] = hs4[b * 128 + off[q]];
#pragma unroll
      for (int g = 0; g < 3; g++) {
        float s = 0.0f;
#pragma unroll
        for (int q = 0; q < 8; q++) {
          s = fmaf(wv[g][q].x, hv[q].x, s);
          s = fmaf(wv[g][q].y, hv[q].y, s);
          s = fmaf(wv[g][q].z, hv[q].z, s);
          s = fmaf(wv[g][q].w, hv[q].w, s);
        }
        acc[g][b] = s;
      }
    }
    // ---- butterfly reduce across the 16 k-chunks (same wave) ----
#pragma unroll
    for (int d = 1; d < 16; d <<= 1) {
#pragma unroll
      for (int g = 0; g < 3; g++)
#pragma unroll
        for (int b = 0; b < 8; b++) acc[g][b] += __shfl_xor(acc[g][b], d);
    }

    // ---- gates: lanes ks<8 handle batch (b0+ks), hidden (j0+jl) ----
    if (ks < 8) {
      int b = b0 + ks;
      int e = j0 + jl;
      float r = sigmoid_f(xr + acc[0][ks] + bh[0]);
      float z = sigmoid_f(xz + acc[1][ks] + bh[1]);
      float n = tanhf(xn + r * (acc[2][ks] + bh[2]));
      int f = e >> 2;
      float4 hp4 = hs4[ks * 128 + (f ^ ((f >> 3) & 7))];
      float hp = ((const float*)&hp4)[e & 3];
      float hnew = (1.0f - z) * n + z * hp;
      hbuf[(cur ^ 1) * BH + (size_t)b * Hh + e] = hnew;
      y[((size_t)t * Bsz + b) * Hh + e] = hnew;
      if (t == Tlen - 1) hfin[(size_t)b * Hh + e] = hnew;
    }

    if (t == Tlen - 1) break;   // nobody consumes the last barrier

    // ---- drain block stores (syncthreads waits vmcnt(0) per wave) ----
    __syncthreads();

    // ---- arrival: release own stamp (no contention; own 128B line) ----
    if (tid == 0) {
      __hip_atomic_store(myslot, base + t + 1, __ATOMIC_RELEASE, __HIP_MEMORY_SCOPE_AGENT);
    }

    // ---- prefetch xg[t+1]: issued now, latency hides under the spin ----
    float nxr = 0.0f, nxz = 0.0f, nxn = 0.0f;
    if (ks < 8) {
      const float* xp = &xg[((size_t)(t + 1) * Bsz + (b0 + ks)) * G3 + j0 + jl];
      nxr = xp[0]; nxz = xp[Hh]; nxn = xp[2 * Hh];
    }

    // ---- wait: wave 0 lane-parallel spin over the group's 32 slots ----
    if (tid < 64) {
      const int target = base + t + 1;
      for (;;) {
        int v = (tid < 32)
            ? __hip_atomic_load(gslots + tid * 32, __ATOMIC_ACQUIRE, __HIP_MEMORY_SCOPE_AGENT)
            : 0x7FFFFFFF;
        if (!__any(v < target)) break;
        __builtin_amdgcn_s_sleep(1);
      }
    }
    __syncthreads();

    xr = nxr; xz = nxz; xn = nxn;
    cur ^= 1;
  }
}

// ---------------------------------------------------------------------------
// Launch
// ---------------------------------------------------------------------------
extern "C" void kernel_launch(void* const* d_in, const int* in_sizes, int n_in,
                              void* d_out, int out_size, void* d_ws, size_t ws_size,
                              hipStream_t stream) {
  const float* x     = (const float*)d_in[0];
  const float* Wih0  = (const float*)d_in[1];
  const float* Whh0  = (const float*)d_in[2];
  const float* bih0  = (const float*)d_in[3];
  const float* bhh0  = (const float*)d_in[4];
  const float* Wih1  = (const float*)d_in[5];
  const float* Whh1  = (const float*)d_in[6];
  const float* bih1  = (const float*)d_in[7];
  const float* bhh1  = (const float*)d_in[8];

  float* out = (float*)d_out;
  float* y1   = out;                       // [T,B,H]
  float* hn0  = out + (size_t)Tlen * BH;   // [B,H]
  float* hn1  = hn0 + BH;                  // [B,H]

  // workspace layout (floats):
  //  [0, 8192)     stamp slots: 8 groups x 32 blocks x 32 ints (32KB)
  //  [8192, +4*BH) h double buffers (slots 0/1 = layer0, 2/3 = layer1)
  //  xg buffer     T*B*3H floats (192 MB)
  //  y0 buffer     T*B*H floats (64 MB)
  float* ws    = (float*)d_ws;
  int*   slots = (int*)d_ws;
  float* hbuf  = ws + 8192;
  float* xgbuf = hbuf + 4 * BH;
  float* y0    = xgbuf + (size_t)Tlen * Bsz * G3;

  const int M = Tlen * Bsz;  // 32768

  // zero stamps + initial h slots (ws is poisoned before every call)
  hipMemsetAsync(slots, 0, 8 * 32 * 32 * sizeof(int), stream);
  hipMemsetAsync(hbuf, 0, BH * sizeof(float), stream);            // layer0 h=0
  hipMemsetAsync(hbuf + 2 * BH, 0, BH * sizeof(float), stream);   // layer1 h=0

  dim3 gemm_grid((M / 128) * (G3 / 128));  // 3072 blocks

  // layer 0 (stamps 1..511)
  gemm_xg<<<gemm_grid, 256, 0, stream>>>(x, Wih0, bih0, xgbuf, M, G3, 256);
  gru_scan<<<256, 256, 0, stream>>>(xgbuf, Whh0, bhh0, y0, hn0, hbuf, slots, 0);

  // layer 1 (stamps 513..1023 -- monotonic past layer 0, no reset needed)
  gemm_xg<<<gemm_grid, 256, 0, stream>>>(y0, Wih1, bih1, xgbuf, M, G3, 512);
  gru_scan<<<256, 256, 0, stream>>>(xgbuf, Whh1, bhh1, y1, hn1, hbuf + 2 * BH, slots, Tlen);
}

// Round 4
// 5866.519 us; speedup vs baseline: 2.7253x; 2.7253x over previous
//
#include <hip/hip_runtime.h>
#include <math.h>

#define Hh   512
#define G3   1536   // 3*H
#define Tlen 512
#define Bsz  64
#define BH   (Bsz*Hh)   // 32768

__device__ __forceinline__ float sigmoid_f(float x) { return 1.0f / (1.0f + expf(-x)); }

// Coherent (IF$-level) scalar store: write-through, bypass L1/L2 dirty state.
__device__ __forceinline__ void store_coh(float* p, float v) {
  asm volatile("global_store_dword %0, %1, off sc0 sc1" :: "v"(p), "v"(v) : "memory");
}

// ---------------------------------------------------------------------------
// GEMM: C[M,N] = A[M,K] @ W[N,K]^T + bias[N]   (fp32, 128x128 tile, 8x8/thread)
// Register double-buffered staging: next k-tile global loads overlap compute.
// M=32768, N=1536, K in {256,512}; all dims divide tiles exactly.
// ---------------------------------------------------------------------------
__global__ __launch_bounds__(256) void gemm_xg(const float* __restrict__ A,
                                               const float* __restrict__ W,
                                               const float* __restrict__ bias,
                                               float* __restrict__ C,
                                               int M, int N, int K) {
  __shared__ float As[16][132];   // [k][m], +4 pad
  __shared__ float Bs[16][132];   // [k][n]
  const int nbm = M >> 7;
  const int bm = blockIdx.x % nbm;
  const int bn = blockIdx.x / nbm;
  const int m0 = bm << 7, n0 = bn << 7;
  const int tid = threadIdx.x;
  const int tx = tid & 15, ty = tid >> 4;

  const int row0 = tid >> 2;          // 0..63
  const int kq0  = (tid & 3) << 2;    // 0,4,8,12

  const float* Ap0 = &A[(size_t)(m0 + row0) * K + kq0];
  const float* Ap1 = &A[(size_t)(m0 + row0 + 64) * K + kq0];
  const float* Wp0 = &W[(size_t)(n0 + row0) * K + kq0];
  const float* Wp1 = &W[(size_t)(n0 + row0 + 64) * K + kq0];

  float4 ra0 = *(const float4*)(Ap0);
  float4 ra1 = *(const float4*)(Ap1);
  float4 rb0 = *(const float4*)(Wp0);
  float4 rb1 = *(const float4*)(Wp1);

  float acc[8][8];
#pragma unroll
  for (int r = 0; r < 8; r++)
#pragma unroll
    for (int c = 0; c < 8; c++) acc[r][c] = 0.0f;

  for (int kk = 0; kk < K; kk += 16) {
    As[kq0+0][row0]    = ra0.x; As[kq0+1][row0]    = ra0.y; As[kq0+2][row0]    = ra0.z; As[kq0+3][row0]    = ra0.w;
    As[kq0+0][row0+64] = ra1.x; As[kq0+1][row0+64] = ra1.y; As[kq0+2][row0+64] = ra1.z; As[kq0+3][row0+64] = ra1.w;
    Bs[kq0+0][row0]    = rb0.x; Bs[kq0+1][row0]    = rb0.y; Bs[kq0+2][row0]    = rb0.z; Bs[kq0+3][row0]    = rb0.w;
    Bs[kq0+0][row0+64] = rb1.x; Bs[kq0+1][row0+64] = rb1.y; Bs[kq0+2][row0+64] = rb1.z; Bs[kq0+3][row0+64] = rb1.w;
    __syncthreads();
    const int kn = kk + 16;
    if (kn < K) {
      ra0 = *(const float4*)(Ap0 + kn);
      ra1 = *(const float4*)(Ap1 + kn);
      rb0 = *(const float4*)(Wp0 + kn);
      rb1 = *(const float4*)(Wp1 + kn);
    }
#pragma unroll
    for (int k = 0; k < 16; k++) {
      float4 a0 = *(const float4*)&As[k][ty << 3];
      float4 a1 = *(const float4*)&As[k][(ty << 3) + 4];
      float4 b0 = *(const float4*)&Bs[k][tx << 3];
      float4 b1 = *(const float4*)&Bs[k][(tx << 3) + 4];
      float ar[8] = {a0.x, a0.y, a0.z, a0.w, a1.x, a1.y, a1.z, a1.w};
      float br[8] = {b0.x, b0.y, b0.z, b0.w, b1.x, b1.y, b1.z, b1.w};
#pragma unroll
      for (int r = 0; r < 8; r++)
#pragma unroll
        for (int c = 0; c < 8; c++) acc[r][c] = fmaf(ar[r], br[c], acc[r][c]);
    }
    __syncthreads();
  }
  float bl[8];
#pragma unroll
  for (int c = 0; c < 8; c++) bl[c] = bias[n0 + (tx << 3) + c];
#pragma unroll
  for (int r = 0; r < 8; r++) {
    int m = m0 + (ty << 3) + r;
    float4 o0 = make_float4(acc[r][0] + bl[0], acc[r][1] + bl[1], acc[r][2] + bl[2], acc[r][3] + bl[3]);
    float4 o1 = make_float4(acc[r][4] + bl[4], acc[r][5] + bl[5], acc[r][6] + bl[6], acc[r][7] + bl[7]);
    *(float4*)&C[(size_t)m * N + n0 + (tx << 3)]     = o0;
    *(float4*)&C[(size_t)m * N + n0 + (tx << 3) + 4] = o1;
  }
}

// ---------------------------------------------------------------------------
// GRU scan (one layer). 256 blocks x 256 threads.
// 8 independent batch-groups of 32 blocks. FENCE-FREE handoff:
//   h stores   -> global_store_dword sc0 sc1 (write-through to IF$)
//   stamp      -> RELAXED agent atomic store after __syncthreads (vmcnt drain)
//   spin       -> RELAXED agent atomic loads (no L2 inv)
//   h staging  -> global_load_dwordx4 sc0 sc1 (bypass L1/L2, read IF$)
// No acquire/release => no per-step L2 writeback/invalidate storms.
// ---------------------------------------------------------------------------
__global__ __launch_bounds__(256, 1) void gru_scan(
    const float* __restrict__ xg,   // [T, B, 3H]
    const float* __restrict__ Whh,  // [3H, H]
    const float* __restrict__ bhh,  // [3H]
    float* __restrict__ y,          // [T, B, H]
    float* __restrict__ hfin,       // [B, H] final hidden
    float* hbuf,                    // 2 slots of [B][H]
    int* slots,                     // 8 groups x 32 blocks x 32-int stride
    int base) {                     // stamp base (0 layer0, Tlen layer1)
  const int tid = threadIdx.x;
  const int jl = tid >> 4;          // 0..15  hidden-j within block
  const int ks = tid & 15;          // 0..15  k-chunk (32 floats each)
  const int bgrp = blockIdx.x & 7;
  const int jgrp = blockIdx.x >> 3; // 0..31
  const int j0 = jgrp << 4;
  const int b0 = bgrp << 3;
  const int k0 = ks << 5;

  int* myslot = slots + (bgrp * 32 + jgrp) * 32;
  int* gslots = slots + bgrp * 32 * 32;

  __shared__ float4 hs4[8 * 128];   // 8 batch rows x 128 float4 (swizzled)

  // persistent W_hh fragment: 3 gates x 32 floats
  float4 wv[3][8];
#pragma unroll
  for (int g = 0; g < 3; g++) {
    const float* wp = &Whh[(size_t)(g * Hh + j0 + jl) * Hh + k0];
#pragma unroll
    for (int q = 0; q < 8; q++) wv[g][q] = *(const float4*)&wp[q * 4];
  }
  float bh[3];
#pragma unroll
  for (int g = 0; g < 3; g++) bh[g] = bhh[g * Hh + j0 + jl];

  // swizzled LDS float4 offsets for this thread's k-chunk
  int off[8];
#pragma unroll
  for (int q = 0; q < 8; q++) off[q] = (ks * 8 + q) ^ (ks & 7);

  // staging geometry: 4 rows per thread, same f, rows brow+{0,2,4,6}
  const int fq = tid & 127;
  const int brow = tid >> 7;                    // 0..1
  const int fswz = fq ^ ((fq >> 3) & 7);

  // prologue: xg[0]
  float xr = 0.0f, xz = 0.0f, xn = 0.0f;
  if (ks < 8) {
    const float* xp = &xg[(size_t)(b0 + ks) * G3 + j0 + jl];
    xr = xp[0]; xz = xp[Hh]; xn = xp[2 * Hh];
  }

  int cur = 0;

  for (int t = 0; t < Tlen; t++) {
    // ---- stage h_prev rows [b0, b0+8) into LDS via coherent loads ----
    const float4* hsrc = (const float4*)(hbuf + cur * BH) + (size_t)(b0 + brow) * 128 + fq;
    float4 h0, h1, h2, h3;
    {
      const float4* p0 = hsrc;
      const float4* p1 = hsrc + 2 * 128;
      const float4* p2 = hsrc + 4 * 128;
      const float4* p3 = hsrc + 6 * 128;
      asm volatile(
          "global_load_dwordx4 %0, %4, off sc0 sc1\n\t"
          "global_load_dwordx4 %1, %5, off sc0 sc1\n\t"
          "global_load_dwordx4 %2, %6, off sc0 sc1\n\t"
          "global_load_dwordx4 %3, %7, off sc0 sc1\n\t"
          "s_waitcnt vmcnt(0)"
          : "=&v"(h0), "=&v"(h1), "=&v"(h2), "=&v"(h3)
          : "v"(p0), "v"(p1), "v"(p2), "v"(p3)
          : "memory");
    }
    hs4[(brow + 0) * 128 + fswz] = h0;
    hs4[(brow + 2) * 128 + fswz] = h1;
    hs4[(brow + 4) * 128 + fswz] = h2;
    hs4[(brow + 6) * 128 + fswz] = h3;
    __syncthreads();

    // ---- partial dots: 3 gates x 8 batches over this thread's 32 k ----
    float acc[3][8];
#pragma unroll
    for (int b = 0; b < 8; b++) {
      float4 hv[8];
#pragma unroll
      for (int q = 0; q < 8; q++) hv[q] = hs4[b * 128 + off[q]];
#pragma unroll
      for (int g = 0; g < 3; g++) {
        float s = 0.0f;
#pragma unroll
        for (int q = 0; q < 8; q++) {
          s = fmaf(wv[g][q].x, hv[q].x, s);
          s = fmaf(wv[g][q].y, hv[q].y, s);
          s = fmaf(wv[g][q].z, hv[q].z, s);
          s = fmaf(wv[g][q].w, hv[q].w, s);
        }
        acc[g][b] = s;
      }
    }
    // ---- butterfly reduce across the 16 k-chunks (same wave) ----
#pragma unroll
    for (int d = 1; d < 16; d <<= 1) {
#pragma unroll
      for (int g = 0; g < 3; g++)
#pragma unroll
        for (int b = 0; b < 8; b++) acc[g][b] += __shfl_xor(acc[g][b], d);
    }

    // ---- gates: lanes ks<8 handle batch (b0+ks), hidden (j0+jl) ----
    if (ks < 8) {
      int b = b0 + ks;
      int e = j0 + jl;
      float r = sigmoid_f(xr + acc[0][ks] + bh[0]);
      float z = sigmoid_f(xz + acc[1][ks] + bh[1]);
      float n = tanhf(xn + r * (acc[2][ks] + bh[2]));
      int f = e >> 2;
      float4 hp4 = hs4[ks * 128 + (f ^ ((f >> 3) & 7))];
      float hp = ((const float*)&hp4)[e & 3];
      float hnew = (1.0f - z) * n + z * hp;
      store_coh(&hbuf[(cur ^ 1) * BH + (size_t)b * Hh + e], hnew);
      y[((size_t)t * Bsz + b) * Hh + e] = hnew;
      if (t == Tlen - 1) hfin[(size_t)b * Hh + e] = hnew;
    }

    if (t == Tlen - 1) break;   // nobody consumes the last barrier

    // ---- drain all waves' stores (hipcc: vmcnt(0) before s_barrier) ----
    __syncthreads();

    // ---- arrival: RELAXED stamp to own 128B slot (h already at IF$) ----
    if (tid == 0) {
      __hip_atomic_store(myslot, base + t + 1, __ATOMIC_RELAXED, __HIP_MEMORY_SCOPE_AGENT);
    }

    // ---- prefetch xg[t+1]: latency hides under the spin ----
    float nxr = 0.0f, nxz = 0.0f, nxn = 0.0f;
    if (ks < 8) {
      const float* xp = &xg[((size_t)(t + 1) * Bsz + (b0 + ks)) * G3 + j0 + jl];
      nxr = xp[0]; nxz = xp[Hh]; nxn = xp[2 * Hh];
    }

    // ---- wait: wave 0 lane-parallel RELAXED spin over group's 32 slots ----
    if (tid < 64) {
      const int target = base + t + 1;
      for (;;) {
        int v = (tid < 32)
            ? __hip_atomic_load(gslots + tid * 32, __ATOMIC_RELAXED, __HIP_MEMORY_SCOPE_AGENT)
            : 0x7FFFFFFF;
        if (!__any(v < target)) break;
        __builtin_amdgcn_s_sleep(1);
      }
    }
    __syncthreads();

    xr = nxr; xz = nxz; xn = nxn;
    cur ^= 1;
  }
}

// ---------------------------------------------------------------------------
// Launch
// ---------------------------------------------------------------------------
extern "C" void kernel_launch(void* const* d_in, const int* in_sizes, int n_in,
                              void* d_out, int out_size, void* d_ws, size_t ws_size,
                              hipStream_t stream) {
  const float* x     = (const float*)d_in[0];
  const float* Wih0  = (const float*)d_in[1];
  const float* Whh0  = (const float*)d_in[2];
  const float* bih0  = (const float*)d_in[3];
  const float* bhh0  = (const float*)d_in[4];
  const float* Wih1  = (const float*)d_in[5];
  const float* Whh1  = (const float*)d_in[6];
  const float* bih1  = (const float*)d_in[7];
  const float* bhh1  = (const float*)d_in[8];

  float* out = (float*)d_out;
  float* y1   = out;                       // [T,B,H]
  float* hn0  = out + (size_t)Tlen * BH;   // [B,H]
  float* hn1  = hn0 + BH;                  // [B,H]

  // workspace layout (floats):
  //  [0, 8192)     stamp slots: 8 groups x 32 blocks x 32 ints (32KB)
  //  [8192, +4*BH) h double buffers (slots 0/1 = layer0, 2/3 = layer1)
  //  xg buffer     T*B*3H floats (192 MB)
  //  y0 buffer     T*B*H floats (64 MB)
  float* ws    = (float*)d_ws;
  int*   slots = (int*)d_ws;
  float* hbuf  = ws + 8192;
  float* xgbuf = hbuf + 4 * BH;
  float* y0    = xgbuf + (size_t)Tlen * Bsz * G3;

  const int M = Tlen * Bsz;  // 32768

  hipMemsetAsync(slots, 0, 8 * 32 * 32 * sizeof(int), stream);
  hipMemsetAsync(hbuf, 0, BH * sizeof(float), stream);            // layer0 h=0
  hipMemsetAsync(hbuf + 2 * BH, 0, BH * sizeof(float), stream);   // layer1 h=0

  dim3 gemm_grid((M / 128) * (G3 / 128));  // 3072 blocks

  // layer 0 (stamps 1..511)
  gemm_xg<<<gemm_grid, 256, 0, stream>>>(x, Wih0, bih0, xgbuf, M, G3, 256);
  gru_scan<<<256, 256, 0, stream>>>(xgbuf, Whh0, bhh0, y0, hn0, hbuf, slots, 0);

  // layer 1 (stamps 513..1023 -- monotonic past layer 0, no reset needed)
  gemm_xg<<<gemm_grid, 256, 0, stream>>>(y0, Wih1, bih1, xgbuf, M, G3, 512);
  gru_scan<<<256, 256, 0, stream>>>(xgbuf, Whh1, bhh1, y1, hn1, hbuf + 2 * BH, slots, Tlen);
}